// Round 7
// baseline (550.686 us; speedup 1.0000x reference)
//
#include <hip/hip_runtime.h>
#include <math.h>

// Problem constants
#define BB 16
#define TT 4096
#define DD 512
#define LOUT 512

typedef __attribute__((ext_vector_type(8))) _Float16 half8;
typedef __attribute__((ext_vector_type(4))) float floatx4;

// ---------------------------------------------------------------------------
// Workspace layout (bytes):
//   A_hi    : _Float16[33554432] @ 0          (hidden hi split)
//   A_lo    : _Float16[33554432] @ 67108864   (hidden lo split)
//   B_hi    : _Float16[786432]   @ 134217728  (conv_w hi, [tap][c][i])
//   B_lo    : _Float16[786432]   @ 135790592
//   a_pre   : float[65536]       @ 137363456
//   w_main  : float[65536]       @ 137625600
//   fire_pos: int[16384]         @ 137887744
//   Fcount  : int[16]            @ 137953280
//   zpage16 : _Float16[512]      @ 137953344  (zero page, conv halo rows)
// ---------------------------------------------------------------------------

// Fused prep: split hidden -> f16 hi/lo, repack conv_w, zero a_pre + zpage.
__global__ void prep(const float* __restrict__ hidden,
                     const float* __restrict__ conv_w,
                     _Float16* __restrict__ A_hi,
                     _Float16* __restrict__ A_lo,
                     _Float16* __restrict__ B_hi,
                     _Float16* __restrict__ B_lo,
                     float* __restrict__ a_pre,
                     _Float16* __restrict__ zp) {
    int idx = blockIdx.x * 256 + threadIdx.x;    // 4194304 threads, 8 elems each
    const float4* src = (const float4*)(hidden + 8 * (size_t)idx);
    float4 v0 = src[0], v1 = src[1];
    float x[8] = {v0.x, v0.y, v0.z, v0.w, v1.x, v1.y, v1.z, v1.w};
    _Float16 hi[8], lo[8];
    #pragma unroll
    for (int j = 0; j < 8; j++) {
        hi[j] = (_Float16)x[j];
        lo[j] = (_Float16)(x[j] - (float)hi[j]);
    }
    *(half8*)(A_hi + 8 * (size_t)idx) = *(half8*)hi;
    *(half8*)(A_lo + 8 * (size_t)idx) = *(half8*)lo;

    if (idx < 786432) {                          // conv_w repack + split
        int tap = idx / 262144;
        int rem = idx - tap * 262144;
        int c = rem >> 9;
        int i = rem & 511;
        float v = conv_w[(c * 512 + i) * 3 + tap];
        _Float16 h = (_Float16)v;
        B_hi[idx] = h;
        B_lo[idx] = (_Float16)(v - (float)h);
    }
    if (idx < 65536) a_pre[idx] = 0.f;
    if (idx < 512)   zp[idx] = (_Float16)0.f;
}

#define GLL16(g, l) __builtin_amdgcn_global_load_lds( \
    (const __attribute__((address_space(1))) void*)(g), \
    (__attribute__((address_space(3))) void*)(l), 16, 0, 0)

// ---------------------------------------------------------------------------
// Split-f16 conv-GEMM, double-buffered minimum-2-phase pipeline (T3 recipe):
//   per kc: STAGE(kc+1 -> other buffer)  [issued FIRST, flies during compute]
//           compute(kc) from current buffer (3 taps x 48 MFMA)
//           __syncthreads()              [vmcnt drain finds loads landed]
// One barrier per kc (was 2). Stage loads via global_load_lds -> zero VGPR
// prefetch state (R2's failure mode avoided). Dynamic LDS 2 x 59392 =
// 118784 B (>64KB static cap; gfx950 supports up to 160KB/workgroup via
// hipFuncSetAttribute, cf. the 128KB 8-phase template) -> 1 block/CU.
// Carried from R5/R6 (verified): salt ((r>>1)&3) swizzle -> 0 conflicts,
// XCD-chunked block swizzle, 256x64 tile, 16x16x32 MFMA, 4x4 frags/wave.
// LDS per buffer: Ahi @0 (272x64B), Alo @17408, Bhi @34816+tap*4096,
//                 Blo @47104+tap*4096.  Buffer 1 at +59392.
// ---------------------------------------------------------------------------

#define STAGE(KBX, WROFF)                                                    \
  do {                                                                       \
    _Pragma("unroll")                                                        \
    for (int j_ = 0; j_ < 15; j_++)                                          \
      if (w + 4 * j_ < 58)                                                   \
        GLL16(wsb + (size_t)(sgoff[j_] + (KBX)), lds + (WROFF) + sloff[j_]); \
  } while (0)

#define COMPUTE(KB, RD)                                                      \
  do {                                                                       \
    _Pragma("unroll")                                                        \
    for (int tap = 0; tap < 3; tap++) {                                      \
      half8 ah[4], al[4], bh[4], bl[4];                                      \
      _Pragma("unroll")                                                      \
      for (int i = 0; i < 4; i++) {                                          \
        ah[i] = *(const half8*)(lds + (RD) + aoff[tap * 4 + i]);             \
        al[i] = *(const half8*)(lds + (RD) + 17408 + aoff[tap * 4 + i]);     \
        bh[i] = *(const half8*)(lds + (RD) + 34816 + tap * 4096 + boff[i]);  \
        bl[i] = *(const half8*)(lds + (RD) + 47104 + tap * 4096 + boff[i]);  \
      }                                                                      \
      _Pragma("unroll")                                                      \
      for (int mi = 0; mi < 4; mi++)                                         \
        _Pragma("unroll")                                                    \
        for (int ni = 0; ni < 4; ni++)                                       \
          acc[mi][ni] = __builtin_amdgcn_mfma_f32_16x16x32_f16(              \
              ah[mi], bh[ni], acc[mi][ni], 0, 0, 0);                         \
      _Pragma("unroll")                                                      \
      for (int mi = 0; mi < 4; mi++)                                         \
        _Pragma("unroll")                                                    \
        for (int ni = 0; ni < 4; ni++)                                       \
          acc[mi][ni] = __builtin_amdgcn_mfma_f32_16x16x32_f16(              \
              al[mi], bh[ni], acc[mi][ni], 0, 0, 0);                         \
      _Pragma("unroll")                                                      \
      for (int mi = 0; mi < 4; mi++)                                         \
        _Pragma("unroll")                                                    \
        for (int ni = 0; ni < 4; ni++)                                       \
          acc[mi][ni] = __builtin_amdgcn_mfma_f32_16x16x32_f16(              \
              ah[mi], bl[ni], acc[mi][ni], 0, 0, 0);                         \
    }                                                                        \
  } while (0)

__launch_bounds__(256, 1)
__global__ void mfma_gemm(const char* __restrict__ wsb,
                          const float* __restrict__ conv_b,
                          const float* __restrict__ out_w,
                          float* __restrict__ a_pre) {
    extern __shared__ __align__(128) char lds[];   // 2 x 59392 B

    const int tid  = threadIdx.x;
    const int w    = tid >> 6;            // wave 0..3 = M sub-tile
    const int lane = tid & 63;

    // XCD-chunked swizzle: all 8 N-tiles of an M-tile co-resident on one XCD.
    const int bid = blockIdx.x;
    const int swz = (bid & 7) * 256 + (bid >> 3);
    const int nt  = swz & 7;
    const int mt  = swz >> 3;
    const int b   = mt >> 4;
    const int t0  = (mt & 15) << 8;
    const int c0  = nt << 6;

    const int srow = lane >> 2;           // staging: lane -> row in unit
    const int schk = lane & 3;

    // ---- staging descriptors: 58 GLL16 units ----
    // g<17: Ahi, 17..33: Alo, 34..57: B (dt x tap x u). Unit g -> wave g&3.
    int sgoff[15], sloff[15];
    #pragma unroll
    for (int j = 0; j < 15; j++) {
        const int g = w + 4 * j;
        int so = 137953344, lo = 0;
        if (g < 58) {
            if (g < 34) {                              // A units
                const int dt = (g >= 17);              // 0=hi 1=lo
                const int u  = dt ? g - 17 : g;
                const int r  = 16 * u + srow;          // LDS row 0..271
                const int t  = t0 - 1 + r;
                const int sw = (schk ^ ((r >> 1) & 3)) << 4;  // pre-swizzled
                so = (t >= 0 && t < TT) ? (dt ? 67108864 : 0)
                                          + (b * TT + t) * 1024 + sw
                                        : 137953344 + sw;
                lo = dt * 17408 + u * 1024;
            } else {                                   // B units
                const int h  = g - 34;
                const int dt = h / 12;
                const int rm = h % 12;
                const int tp = rm >> 2;
                const int u  = rm & 3;
                const int r  = 16 * u + srow;
                const int sw = (schk ^ ((r >> 1) & 3)) << 4;
                so = (dt ? 135790592 : 134217728) + tp * 524288
                     + (c0 + r) * 1024 + sw;
                lo = 34816 + dt * 12288 + tp * 4096 + u * 1024;
            }
        }
        sgoff[j] = so;
        sloff[j] = lo;
    }

    // ---- LDS frag read offsets (salt-matched swizzle) ----
    int aoff[12], boff[4];
    #pragma unroll
    for (int tap = 0; tap < 3; tap++)
        #pragma unroll
        for (int i = 0; i < 4; i++) {
            const int ra = 64 * w + 16 * i + (lane & 15) + tap;
            aoff[tap * 4 + i] = ra * 64
                + (((lane >> 4) ^ ((ra >> 1) & 3)) << 4);
        }
    #pragma unroll
    for (int i = 0; i < 4; i++) {
        const int rb = 16 * i + (lane & 15);
        boff[i] = rb * 64 + (((lane >> 4) ^ ((rb >> 1) & 3)) << 4);
    }

    floatx4 acc[4][4];
    #pragma unroll
    for (int mi = 0; mi < 4; mi++)
        #pragma unroll
        for (int ni = 0; ni < 4; ni++)
            acc[mi][ni] = (floatx4)(0.f);

    // epilogue constants: col n = c0 + 16*ni + (lane&15)
    float u_n[4], cb_n[4];
    #pragma unroll
    for (int ni = 0; ni < 4; ni++) {
        int n = c0 + 16 * ni + (lane & 15);
        u_n[ni]  = out_w[n];
        cb_n[ni] = conv_b[n];
    }

    // ---- prologue: stage kc0 -> buf0 ----
    STAGE(0, 0);
    __syncthreads();

    // ---- main loop: 16 kc, unrolled x2 for buffer parity ----
    // per kc: stage(kc+1 -> other buf) FIRST, compute(kc), one barrier.
    for (int kp = 0; kp < 8; kp++) {
        const int KB = kp << 7;                    // kc = 2kp -> kb = 128*kp
        STAGE(KB + 64, 59392);                     // stage kc+1 (always <16)
        COMPUTE(KB, 0);
        __syncthreads();
        if (kp < 7) STAGE(KB + 128, 0);            // stage kc+2
        COMPUTE(KB + 64, 59392);
        __syncthreads();
    }

    // epilogue: s[mi][reg] = sum_ni relu(acc + cb)*u ; reduce over lane&15 ; atomic
    float s[4][4];
    #pragma unroll
    for (int mi = 0; mi < 4; mi++)
        #pragma unroll
        for (int rg = 0; rg < 4; rg++) {
            float t = 0.f;
            #pragma unroll
            for (int ni = 0; ni < 4; ni++) {
                float y = acc[mi][ni][rg] + cb_n[ni];
                y = y > 0.f ? y : 0.f;
                t = fmaf(y, u_n[ni], t);
            }
            s[mi][rg] = t;
        }
    #pragma unroll
    for (int mi = 0; mi < 4; mi++)
        #pragma unroll
        for (int rg = 0; rg < 4; rg++) {
            #pragma unroll
            for (int off = 1; off < 16; off <<= 1)
                s[mi][rg] += __shfl_xor(s[mi][rg], off);
        }
    if ((lane & 15) == 0) {
        const int q = lane >> 4;
        #pragma unroll
        for (int mi = 0; mi < 4; mi++)
            #pragma unroll
            for (int rg = 0; rg < 4; rg++) {
                int m = 64 * w + 16 * mi + 4 * q + rg;
                atomicAdd(&a_pre[b * TT + t0 + m], s[mi][rg]);
            }
    }
}

// ---------------------------------------------------------------------------
// Per-batch: sigmoid -> token_num -> rescale -> PARALLEL CIF scan.
// F_t = floor(P_t), fire_t = (F_t > F_{t-1}), cur_t = fire ? F_t - P_{t-1} : a_t
// with P = double prefix sum (chunk sums + Hillis-Steele + serial finish).
// ---------------------------------------------------------------------------
__global__ void cif_scan(const float* __restrict__ a_pre,
                         const float* __restrict__ mask,
                         const float* __restrict__ tll,
                         const float* __restrict__ out_bias,
                         float* __restrict__ out_tn,
                         float* __restrict__ out_alphas,
                         float* __restrict__ out_peak,
                         float* __restrict__ w_main,
                         int* __restrict__ fire_pos,
                         int* __restrict__ Fcount) {
    __shared__ float alpha_s[TT];
    __shared__ float wm_s[TT];
    __shared__ float fires_s[TT];
    __shared__ int   fp_s[1024];
    __shared__ double red[256];
    __shared__ float ratio_s;
    __shared__ int   F_sh;

    const int b = blockIdx.x;
    const int tid = threadIdx.x;
    const float ob = out_bias[0];

    // ---- sigmoid + masked alphas + token_num reduction ----
    double lsum = 0.0;
    for (int t = tid; t < TT; t += 256) {
        float a = a_pre[b * TT + t] + ob;
        float e = expf(-fabsf(a));
        float sg = (a >= 0.f) ? (1.f / (1.f + e)) : (e / (1.f + e));
        float af = sg;
        af = af > 0.f ? af : 0.f;
        af = af * mask[b * TT + t];
        alpha_s[t] = af;
        lsum += (double)af;
    }
    red[tid] = lsum;
    __syncthreads();
    for (int off = 128; off > 0; off >>= 1) {
        if (tid < off) red[tid] += red[tid + off];
        __syncthreads();
    }
    if (tid == 0) {
        float tn = (float)red[0];
        out_tn[b] = tn;
        ratio_s = tll[b] / tn;
    }
    __syncthreads();
    const float ratio = ratio_s;

    // ---- rescale: thread tid owns contiguous chunk [16*tid, 16*tid+16) ----
    const int t0c = tid * 16;
    float av[16];
    double csum = 0.0;
    #pragma unroll
    for (int j = 0; j < 16; j++) {
        float a = alpha_s[t0c + j] * ratio;
        av[j] = a;
        csum += (double)a;
    }
    #pragma unroll
    for (int j = 0; j < 16; j++)
        alpha_s[t0c + j] = av[j];
    red[tid] = csum;
    __syncthreads();

    // ---- inclusive Hillis-Steele scan of 256 chunk sums (double) ----
    #pragma unroll
    for (int off = 1; off < 256; off <<= 1) {
        double v = (tid >= off) ? red[tid - off] : 0.0;
        __syncthreads();
        red[tid] += v;
        __syncthreads();
    }
    const double base = red[tid] - csum;   // exclusive prefix at chunk start

    // ---- per-chunk serial finish (all 256 threads in parallel) ----
    double P = base;
    int Fp = (int)P;                       // floor (P >= 0)
    #pragma unroll
    for (int j = 0; j < 16; j++) {
        const float a = av[j];
        const double Pp = P;
        P += (double)a;
        const int F = (int)P;
        fires_s[t0c + j] = (float)(P - (double)Fp);          // In (pre-reset)
        const bool fire = F > Fp;
        wm_s[t0c + j] = fire ? (float)((double)F - Pp) : a;  // cur
        if (fire && Fp < 1024) fp_s[Fp] = t0c + j;
        Fp = F;
    }
    if (tid == 255) {
        F_sh = (Fp > 1024) ? 1024 : Fp;
        Fcount[b] = F_sh;
    }
    __syncthreads();

    // ---- coalesced writes to global ----
    for (int t = tid; t < TT; t += 256) {
        out_alphas[b * TT + t] = alpha_s[t];
        out_peak[b * TT + t]   = fires_s[t];
        w_main[b * TT + t]     = wm_s[t];
    }
    const int F = F_sh;
    for (int s = tid; s < F; s += 256)
        fire_pos[b * 1024 + s] = fp_s[s];
}

// acoustic_embeds[b,s,:] = spill(prev fire) + sum over contiguous t-segment.
__global__ void cif_scatter(const float* __restrict__ hidden,
                            const float* __restrict__ alphas,
                            const float* __restrict__ w_main,
                            const int* __restrict__ fire_pos,
                            const int* __restrict__ Fcount,
                            float* __restrict__ out_emb) {
    const int s = blockIdx.x;
    const int b = blockIdx.y;
    const int tid = threadIdx.x;   // 0..127 -> d = 4*tid
    const int F = Fcount[b];

    float4 acc = make_float4(0.f, 0.f, 0.f, 0.f);
    if (s < F) {
        const int t_hi = fire_pos[b * 1024 + s];
        const int t_lo = (s > 0) ? fire_pos[b * 1024 + s - 1] : 0;
        for (int t = t_lo; t <= t_hi; t++) {
            float w;
            if (s > 0 && t == t_lo)
                w = alphas[b * TT + t] - w_main[b * TT + t];
            else
                w = w_main[b * TT + t];
            const float4 h = *(const float4*)(hidden + ((size_t)(b * TT + t)) * DD + 4 * tid);
            acc.x = fmaf(w, h.x, acc.x);
            acc.y = fmaf(w, h.y, acc.y);
            acc.z = fmaf(w, h.z, acc.z);
            acc.w = fmaf(w, h.w, acc.w);
        }
    }
    *(float4*)(out_emb + ((size_t)(b * LOUT + s)) * DD + 4 * tid) = acc;
}

extern "C" void kernel_launch(void* const* d_in, const int* in_sizes, int n_in,
                              void* d_out, int out_size, void* d_ws, size_t ws_size,
                              hipStream_t stream) {
    const float* hidden  = (const float*)d_in[0];
    const float* mask    = (const float*)d_in[1];
    const float* tll     = (const float*)d_in[2];
    const float* conv_w  = (const float*)d_in[3];
    const float* conv_b  = (const float*)d_in[4];
    const float* out_w   = (const float*)d_in[5];
    const float* out_b   = (const float*)d_in[6];

    float* out        = (float*)d_out;
    float* out_emb    = out;
    float* out_tn     = out + 4194304;
    float* out_alphas = out + 4194320;
    float* out_peak   = out + 4259856;

    char* ws = (char*)d_ws;
    _Float16* A_hi   = (_Float16*)(ws);
    _Float16* A_lo   = (_Float16*)(ws + 67108864);
    _Float16* B_hi   = (_Float16*)(ws + 134217728);
    _Float16* B_lo   = (_Float16*)(ws + 135790592);
    float* a_pre     = (float*)(ws + 137363456);
    float* w_main    = (float*)(ws + 137625600);
    int*   fire_pos  = (int*)(ws + 137887744);
    int*   Fcount    = (int*)(ws + 137953280);
    _Float16* zpage  = (_Float16*)(ws + 137953344);

    // allow >64KB dynamic LDS for the double-buffered GEMM (gfx950: 160KB/wg)
    static bool attr_set = false;
    if (!attr_set) {
        hipFuncSetAttribute((const void*)mfma_gemm,
                            hipFuncAttributeMaxDynamicSharedMemorySize, 118784);
        attr_set = true;
    }

    prep<<<16384, 256, 0, stream>>>(hidden, conv_w, A_hi, A_lo, B_hi, B_lo,
                                    a_pre, zpage);
    mfma_gemm<<<2048, 256, 118784, stream>>>(ws, conv_b, out_w, a_pre);
    cif_scan<<<16, 256, 0, stream>>>(a_pre, mask, tll, out_b,
                                     out_tn, out_alphas, out_peak,
                                     w_main, fire_pos, Fcount);
    cif_scatter<<<dim3(512, 16), 128, 0, stream>>>(hidden, out_alphas, w_main,
                                                   fire_pos, Fcount, out_emb);
}